// Round 1
// baseline (1547.703 us; speedup 1.0000x reference)
//
#include <hip/hip_runtime.h>

// ---------------------------------------------------------------------------
// MHA forward: out = LN(attn_proj + residual), attn = softmax(QK^T/sqrt(64))
// B=4, S=2048, H=16, Dh=64, E=1024
// d_out = [ out (4*2048*1024 f32) | attn (4*16*2048*2048 f32) ]
// ---------------------------------------------------------------------------

typedef __bf16 bf16_t;
typedef __bf16 bf16x4 __attribute__((ext_vector_type(4)));
typedef __bf16 bf16x8 __attribute__((ext_vector_type(8)));
typedef float f32x4 __attribute__((ext_vector_type(4)));

#define MFMA16(a, b, c) __builtin_amdgcn_mfma_f32_16x16x32_bf16((a), (b), (c), 0, 0, 0)

// ---------------------------------------------------------------------------
// GEMM: C[m,n] = sum_k A[m,k] * W[n,k]   (x @ W.T), M=8192, N=1024, K=1024
// mode 0: out = bf16, scattered to [b,h,s,d] head layout, scaled
// mode 1: out = f32 row-major [M,1024]
// ---------------------------------------------------------------------------
__global__ __launch_bounds__(256) void gemm_xwT(
    const float* __restrict__ A, const float* __restrict__ W,
    void* __restrict__ out, int mode, float scale)
{
    constexpr int K = 1024;
    __shared__ bf16_t As[128][72];   // +8 pad: 144B row stride, 16B aligned
    __shared__ bf16_t Ws[128][72];

    const int t    = threadIdx.x;
    const int lane = t & 63;
    const int wv   = t >> 6;
    const int m0   = blockIdx.y * 128;
    const int n0   = blockIdx.x * 128;
    const int wr   = (wv >> 1) * 64;   // wave's 64x64 quadrant
    const int wc   = (wv & 1) * 64;

    f32x4 acc[4][4] = {};

    const int fr = lane & 15;          // fragment row (m or n within 16-tile)
    const int fk = (lane >> 4) << 3;   // fragment k offset (quad*8)

    for (int k0 = 0; k0 < K; k0 += 64) {
        __syncthreads();
        // stage 128x64 f32 -> bf16 LDS for both A and W
        for (int i = 0; i < 8; ++i) {
            int slot = t + i * 256;            // 0..2047
            int r    = slot >> 4;              // 0..127
            int cg   = (slot & 15) << 2;       // 0..60
            float4 av = *(const float4*)(A + (size_t)(m0 + r) * K + k0 + cg);
            float4 wvv = *(const float4*)(W + (size_t)(n0 + r) * K + k0 + cg);
            bf16x4 ab, wb;
            ab[0] = (bf16_t)av.x;  ab[1] = (bf16_t)av.y;
            ab[2] = (bf16_t)av.z;  ab[3] = (bf16_t)av.w;
            wb[0] = (bf16_t)wvv.x; wb[1] = (bf16_t)wvv.y;
            wb[2] = (bf16_t)wvv.z; wb[3] = (bf16_t)wvv.w;
            *(bf16x4*)&As[r][cg] = ab;
            *(bf16x4*)&Ws[r][cg] = wb;
        }
        __syncthreads();
        for (int ks = 0; ks < 2; ++ks) {
            const int kk = ks * 32 + fk;
            bf16x8 af[4], bw[4];
            for (int i = 0; i < 4; ++i) af[i] = *(const bf16x8*)&As[wr + i * 16 + fr][kk];
            for (int j = 0; j < 4; ++j) bw[j] = *(const bf16x8*)&Ws[wc + j * 16 + fr][kk];
            for (int i = 0; i < 4; ++i)
                for (int j = 0; j < 4; ++j)
                    acc[i][j] = MFMA16(af[i], bw[j], acc[i][j]);
        }
    }

    // epilogue: C layout col=lane&15, row=quad*4+reg
    const int cq = lane & 15;
    const int rq = (lane >> 4) << 2;
    for (int i = 0; i < 4; ++i) {
        for (int j = 0; j < 4; ++j) {
            const int n = n0 + wc + j * 16 + cq;
            for (int r = 0; r < 4; ++r) {
                const int m = m0 + wr + i * 16 + rq + r;
                const float v = acc[i][j][r] * scale;
                if (mode == 0) {
                    const int b = m >> 11, s = m & 2047;
                    const int h = n >> 6,  d = n & 63;
                    ((bf16_t*)out)[((size_t)((b * 16 + h) * 2048 + s) << 6) + d] = (bf16_t)v;
                } else {
                    ((float*)out)[(size_t)m * 1024 + n] = v;
                }
            }
        }
    }
}

// ---------------------------------------------------------------------------
// Attention: per (bh, 64-row Q tile). Pass 1: row sums of exp(S). Pass 2:
// recompute S, write P=exp(S)/l to attn (f32), accumulate O = P @ V.
// ---------------------------------------------------------------------------
__global__ __launch_bounds__(256) void attn_kernel(
    const bf16_t* __restrict__ qh, const bf16_t* __restrict__ kh,
    const bf16_t* __restrict__ vh, float* __restrict__ attn_out,
    float* __restrict__ o_out)
{
    __shared__ bf16_t Qs[64][72];     //  9216 B
    __shared__ bf16_t Ks[128][72];    // 18432 B
    __shared__ bf16_t Vt[64][136];    // 17408 B  [dv][n], padded
    __shared__ bf16_t Ps[64][136];    // 17408 B
    __shared__ float  Linv[64];       //   256 B   -> total ~62.7 KB

    const int t    = threadIdx.x;
    const int lane = t & 63;
    const int wv   = t >> 6;
    const int qt   = blockIdx.x;      // 0..31
    const int bh   = blockIdx.y;      // 0..63
    const int sq0  = qt * 64;
    const size_t hbase = (size_t)bh * 2048 * 64;   // base of this head's [S,64]

    // stage Q tile [64 x 64]
    for (int i = 0; i < 2; ++i) {
        int slot = t + i * 256;        // 0..511
        int r = slot >> 3, g = (slot & 7) << 3;
        *(bf16x8*)&Qs[r][g] = *(const bf16x8*)(qh + hbase + (size_t)(sq0 + r) * 64 + g);
    }
    __syncthreads();

    const int fr    = lane & 15;
    const int fk    = (lane >> 4) << 3;
    const int rq    = (lane >> 4) << 2;
    const int rbase = wv * 16;         // wave's 16-row strip

    const bf16x8 qa0 = *(const bf16x8*)&Qs[rbase + fr][fk];
    const bf16x8 qa1 = *(const bf16x8*)&Qs[rbase + fr][32 + fk];

    // ---- pass 1: l = sum_k exp(s) per row (no max needed: |s| <~ 7)
    float lsum[4] = {0.f, 0.f, 0.f, 0.f};
    for (int kt = 0; kt < 16; ++kt) {
        __syncthreads();
        for (int i = 0; i < 4; ++i) {
            int slot = t + i * 256;    // 0..1023
            int r = slot >> 3, g = (slot & 7) << 3;
            *(bf16x8*)&Ks[r][g] =
                *(const bf16x8*)(kh + hbase + (size_t)(kt * 128 + r) * 64 + g);
        }
        __syncthreads();
        for (int ct = 0; ct < 8; ++ct) {
            f32x4 c = {0.f, 0.f, 0.f, 0.f};
            bf16x8 b0 = *(const bf16x8*)&Ks[ct * 16 + fr][fk];
            bf16x8 b1 = *(const bf16x8*)&Ks[ct * 16 + fr][32 + fk];
            c = MFMA16(qa0, b0, c);
            c = MFMA16(qa1, b1, c);
            lsum[0] += __expf(c[0]); lsum[1] += __expf(c[1]);
            lsum[2] += __expf(c[2]); lsum[3] += __expf(c[3]);
        }
    }
    for (int m = 1; m < 16; m <<= 1)
        for (int r = 0; r < 4; ++r)
            lsum[r] += __shfl_xor(lsum[r], m, 64);
    if ((lane & 15) == 0)
        for (int r = 0; r < 4; ++r)
            Linv[rbase + rq + r] = 1.0f / lsum[r];
    __syncthreads();
    float inv[4];
    for (int r = 0; r < 4; ++r) inv[r] = Linv[rbase + rq + r];

    // ---- pass 2: P = exp(S)*inv -> attn out + LDS; O += P @ V
    f32x4 oacc[4] = {};
    for (int kt = 0; kt < 16; ++kt) {
        __syncthreads();
        // stage K (coalesced) and V (transposed into Vt[dv][n])
        for (int i = 0; i < 4; ++i) {
            int slot = t + i * 256;
            int r = slot >> 3, g = (slot & 7) << 3;
            *(bf16x8*)&Ks[r][g] =
                *(const bf16x8*)(kh + hbase + (size_t)(kt * 128 + r) * 64 + g);
            int n = t & 127;                    // conflict-free Vt writes
            int dvg = ((t >> 7) + 2 * i) << 3;
            bf16x8 vv = *(const bf16x8*)(vh + hbase + (size_t)(kt * 128 + n) * 64 + dvg);
            for (int j = 0; j < 8; ++j) Vt[dvg + j][n] = vv[j];
        }
        __syncthreads();
        for (int ct = 0; ct < 8; ++ct) {
            f32x4 c = {0.f, 0.f, 0.f, 0.f};
            bf16x8 b0 = *(const bf16x8*)&Ks[ct * 16 + fr][fk];
            bf16x8 b1 = *(const bf16x8*)&Ks[ct * 16 + fr][32 + fk];
            c = MFMA16(qa0, b0, c);
            c = MFMA16(qa1, b1, c);
            for (int r = 0; r < 4; ++r) {
                float p = __expf(c[r]) * inv[r];
                Ps[rbase + rq + r][ct * 16 + fr] = (bf16_t)p;
            }
        }
        __syncthreads();
        // coalesced f32 attn write from Ps
        const size_t abase = ((size_t)bh * 2048 + sq0) * 2048 + kt * 128;
        for (int i = 0; i < 8; ++i) {
            int slot = t + i * 256;          // 0..2047
            int r = slot >> 5, cg = (slot & 31) << 2;
            bf16x4 pv = *(const bf16x4*)&Ps[r][cg];
            float4 f;
            f.x = (float)pv[0]; f.y = (float)pv[1];
            f.z = (float)pv[2]; f.w = (float)pv[3];
            *(float4*)(attn_out + abase + (size_t)r * 2048 + cg) = f;
        }
        // PV MFMA: A=Ps rows (strip), B=Vt
        bf16x8 pa[4];
        for (int ks = 0; ks < 4; ++ks)
            pa[ks] = *(const bf16x8*)&Ps[rbase + fr][ks * 32 + fk];
        for (int dt = 0; dt < 4; ++dt)
            for (int ks = 0; ks < 4; ++ks) {
                bf16x8 bv = *(const bf16x8*)&Vt[dt * 16 + fr][ks * 32 + fk];
                oacc[dt] = MFMA16(pa[ks], bv, oacc[dt]);
            }
    }

    // write O tile -> o_out [B,S,H*64] f32
    {
        const int b = bh >> 4, h = bh & 15;
        for (int dt = 0; dt < 4; ++dt)
            for (int r = 0; r < 4; ++r) {
                const int m = sq0 + rbase + rq + r;
                const int dv = dt * 16 + fr;
                o_out[(size_t)(b * 2048 + m) * 1024 + h * 64 + dv] = oacc[dt][r];
            }
    }
}

// ---------------------------------------------------------------------------
// LayerNorm(fc + residual) -> out
// ---------------------------------------------------------------------------
__global__ __launch_bounds__(256) void ln_kernel(
    const float* __restrict__ x, const float* __restrict__ resid,
    const float* __restrict__ gamma, const float* __restrict__ beta,
    float* __restrict__ out)
{
    const int row = blockIdx.x;
    const int t   = threadIdx.x;
    const size_t base = (size_t)row * 1024 + t * 4;
    float4 v = *(const float4*)(x + base);
    float4 rz = *(const float4*)(resid + base);
    v.x += rz.x; v.y += rz.y; v.z += rz.z; v.w += rz.w;
    float s  = v.x + v.y + v.z + v.w;
    float sq = v.x * v.x + v.y * v.y + v.z * v.z + v.w * v.w;
    for (int m = 1; m < 64; m <<= 1) {
        s  += __shfl_xor(s, m, 64);
        sq += __shfl_xor(sq, m, 64);
    }
    __shared__ float ws_s[4], ws_q[4];
    const int wv = t >> 6;
    if ((t & 63) == 0) { ws_s[wv] = s; ws_q[wv] = sq; }
    __syncthreads();
    s  = ws_s[0] + ws_s[1] + ws_s[2] + ws_s[3];
    sq = ws_q[0] + ws_q[1] + ws_q[2] + ws_q[3];
    const float mu  = s * (1.0f / 1024.0f);
    const float var = sq * (1.0f / 1024.0f) - mu * mu;
    const float rs  = rsqrtf(var + 1e-6f);
    float4 g = *(const float4*)(gamma + t * 4);
    float4 b = *(const float4*)(beta + t * 4);
    float4 y;
    y.x = (v.x - mu) * rs * g.x + b.x;
    y.y = (v.y - mu) * rs * g.y + b.y;
    y.z = (v.z - mu) * rs * g.z + b.z;
    y.w = (v.w - mu) * rs * g.w + b.w;
    *(float4*)(out + base) = y;
}

// ---------------------------------------------------------------------------
extern "C" void kernel_launch(void* const* d_in, const int* in_sizes, int n_in,
                              void* d_out, int out_size, void* d_ws, size_t ws_size,
                              hipStream_t stream)
{
    const float* q       = (const float*)d_in[0];
    const float* k       = (const float*)d_in[1];
    const float* v       = (const float*)d_in[2];
    const float* w_q     = (const float*)d_in[3];
    const float* w_k     = (const float*)d_in[4];
    const float* w_v     = (const float*)d_in[5];
    const float* w_fc    = (const float*)d_in[6];
    const float* ln_g    = (const float*)d_in[7];
    const float* ln_b    = (const float*)d_in[8];

    float* out      = (float*)d_out;
    float* attn_out = out + (size_t)4 * 2048 * 1024;   // 8388608 floats

    char* ws = (char*)d_ws;
    bf16_t* qh    = (bf16_t*)(ws);                       // 16 MB
    bf16_t* kh    = (bf16_t*)(ws + (size_t)16777216);    // 16 MB
    bf16_t* vh    = (bf16_t*)(ws + (size_t)33554432);    // 16 MB
    float*  o_f32 = (float*)(ws + (size_t)50331648);     // 32 MB
    float*  fc    = (float*)(ws);                        // reuse qh+kh region

    dim3 gg(8, 64);   // N/128, M/128
    gemm_xwT<<<gg, 256, 0, stream>>>(q, w_q, qh, 0, 0.125f);  // fold 1/sqrt(64)
    gemm_xwT<<<gg, 256, 0, stream>>>(k, w_k, kh, 0, 1.0f);
    gemm_xwT<<<gg, 256, 0, stream>>>(v, w_v, vh, 0, 1.0f);

    attn_kernel<<<dim3(32, 64), 256, 0, stream>>>(qh, kh, vh, attn_out, o_f32);

    gemm_xwT<<<gg, 256, 0, stream>>>(o_f32, w_fc, fc, 1, 1.0f);

    ln_kernel<<<8192, 256, 0, stream>>>(fc, q, ln_g, ln_b, out);
}